// Round 1
// baseline (127.379 us; speedup 1.0000x reference)
//
#include <hip/hip_runtime.h>

// Undistort (inverse radial distortion resample), C=3, H=W=2048, fp32.
// Math: rd*cos(theta) == xur/(1-k*ru^2), rd*sin(theta) == yur/(1-k*ru^2),
// so the whole coordinate map is one FMA chain + one reciprocal (no trig).

#ifndef UND_C
#define UND_C 3
#define UND_H 2048
#define UND_W 2048
#endif

__global__ __launch_bounds__(256) void undistort_kernel(
    const float* __restrict__ im,   // [C][H][W]
    const float* __restrict__ kp,   // [1]
    const float* __restrict__ dxp,  // [1]
    const float* __restrict__ dyp,  // [1]
    float* __restrict__ out)        // [C][H][W]
{
    constexpr int C = UND_C, H = UND_H, W = UND_W;
    const int idx = blockIdx.x * blockDim.x + threadIdx.x;
    if (idx >= H * W) return;

    const int x = idx & (W - 1);
    const int y = idx >> 11;  // W == 2048

    const float k  = kp[0];
    const float dx = dxp[0];
    const float dy = dyp[0];

    // Undistorted normalized coords (exact /W, /H: powers of two).
    const float xur = ((float)x - dx) * (1.0f / (float)W) - 0.5f;
    const float yur = ((float)y - dy) * (1.0f / (float)H) - 0.5f;

    const float r2 = xur * xur + yur * yur;
    const float s  = 1.0f / (1.0f - k * r2);   // rd/ru

    const float xd = (xur * s + 0.5f) * (float)W + dx;
    const float yd = (yur * s + 0.5f) * (float)H + dy;

    const float xf = floorf(xd);
    const float yf = floorf(yd);
    const float xc = ceilf(xd);
    const float yc = ceilf(yd);

    const float ox  = xd - xf;
    const float oy  = yd - yf;
    const float onx = 1.0f - ox;
    const float ony = 1.0f - oy;

    const bool valid = (xf >= 0.0f) & (xc < (float)W) & (yf >= 0.0f) & (yc < (float)H);

    int xfi = (int)xf; xfi = xfi < 0 ? 0 : (xfi > W - 1 ? W - 1 : xfi);
    int xci = (int)xc; xci = xci < 0 ? 0 : (xci > W - 1 ? W - 1 : xci);
    int yfi = (int)yf; yfi = yfi < 0 ? 0 : (yfi > H - 1 ? H - 1 : yfi);
    int yci = (int)yc; yci = yci < 0 ? 0 : (yci > H - 1 ? H - 1 : yci);

    const float w00 = onx * ony;
    const float w01 = ox * ony;
    const float w10 = onx * oy;
    const float w11 = ox * oy;

    const int rowf = yfi * W;
    const int rowc = yci * W;

#pragma unroll
    for (int c = 0; c < C; ++c) {
        const float* __restrict__ p = im + (size_t)c * (H * W);
        const float v00 = p[rowf + xfi];
        const float v01 = p[rowf + xci];
        const float v10 = p[rowc + xfi];
        const float v11 = p[rowc + xci];
        float r = w00 * v00 + w01 * v01 + w10 * v10 + w11 * v11;
        out[(size_t)c * (H * W) + idx] = valid ? r : 0.0f;
    }
}

extern "C" void kernel_launch(void* const* d_in, const int* in_sizes, int n_in,
                              void* d_out, int out_size, void* d_ws, size_t ws_size,
                              hipStream_t stream) {
    (void)in_sizes; (void)n_in; (void)d_ws; (void)ws_size; (void)out_size;
    const float* im = (const float*)d_in[0];
    const float* k  = (const float*)d_in[1];
    const float* dx = (const float*)d_in[2];
    const float* dy = (const float*)d_in[3];
    float* out = (float*)d_out;

    constexpr int H = UND_H, W = UND_W;
    const int n = H * W;
    const int block = 256;
    const int grid = (n + block - 1) / block;
    undistort_kernel<<<grid, block, 0, stream>>>(im, k, dx, dy, out);
}